// Round 14
// baseline (177.252 us; speedup 1.0000x reference)
//
#include <hip/hip_runtime.h>
#include <stdint.h>

typedef _Float16 h8v __attribute__((ext_vector_type(8)));
typedef _Float16 h4v __attribute__((ext_vector_type(4)));
typedef float f4v __attribute__((ext_vector_type(4)));
typedef _Float16 f16;

#define NB 8
#define CC 128
#define CB 64
#define NN 4096
#define L2E 1.4426950408889634f

// ---------------------------------------------------------------------------
// Kernel 0: pack weights into f16 MFMA-fragment order (unchanged from R13).
// ---------------------------------------------------------------------------
__global__ __launch_bounds__(256) void pack_w(
    const float* __restrict__ wth, const float* __restrict__ wph,
    const float* __restrict__ wg,  const float* __restrict__ wl,
    f16* __restrict__ wthp, f16* __restrict__ wphp,
    f16* __restrict__ wgp,  f16* __restrict__ wlp)
{
    const int t = blockIdx.x * 256 + threadIdx.x;      // 2048 threads
    for (int i = t; i < 8192; i += 2048){
        const int j = i & 7, lane = (i >> 3) & 63, kc = (i >> 9) & 3, ks = i >> 11;
        const int row = ks * 16 + (lane & 15);
        const int col = kc * 32 + ((lane >> 4) & 3) * 8 + j;
        wthp[i] = (f16)(wth[row * CC + col] * L2E);
        wphp[i] = (f16)(wph[row * CC + col]);
        wgp [i] = (f16)(wg [row * CC + col]);
    }
    for (int i = t; i < 8192; i += 2048){
        const int j = i & 7, lane = (i >> 3) & 63, kc = (i >> 9) & 1, cs = i >> 10;
        const int row = cs * 16 + (lane & 15);
        const int col = kc * 32 + ((lane >> 4) & 3) * 8 + j;
        wlp[i] = (f16)(wl[row * CB + col]);
    }
}

// ---------------------------------------------------------------------------
// Kernel 1: projections (unchanged from R13).
// ---------------------------------------------------------------------------
__global__ __launch_bounds__(256) void proj_kernel(
    const float* __restrict__ x, const f16* __restrict__ wthp,
    const f16* __restrict__ wphp, const f16* __restrict__ wgp,
    f16* __restrict__ thetaT, f16* __restrict__ phiT, f16* __restrict__ gbuf)
{
    __shared__ __align__(16) f16 xT[64][136];
    __shared__ __align__(16) f16 rep[4][16 * 72];
    const int b  = blockIdx.x & 7;
    const int n0 = (blockIdx.x >> 3) << 6;
    const int t  = threadIdx.x;

    #pragma unroll
    for (int i = 0; i < 8; i++){
        int v  = t + 256 * i;
        int c  = v >> 4;
        int j0 = (v & 15) << 2;
        const f4v xv = *(const f4v*)&x[((size_t)(b * CC + c)) * NN + n0 + j0];
        #pragma unroll
        for (int jj = 0; jj < 4; jj++) xT[j0 + jj][c] = (f16)xv[jj];
    }
    __syncthreads();

    const int w = t >> 6, lane = t & 63, quad = lane >> 4, l15 = lane & 15;
    const int rrow = lane >> 3, rcol = (lane & 7) * 8;

    h8v bx[4];
    #pragma unroll
    for (int kc = 0; kc < 4; kc++)
        bx[kc] = *(const h8v*)&xT[w * 16 + l15][kc * 32 + quad * 8];

    #pragma unroll
    for (int m3 = 0; m3 < 2; m3++){
        const f16* WP = (m3 == 0) ? wthp : wphp;
        f16* OUT      = (m3 == 0) ? thetaT : phiT;
        for (int ks = 0; ks < 4; ks++){
            f4v acc = {0.f, 0.f, 0.f, 0.f};
            #pragma unroll
            for (int kc = 0; kc < 4; kc++){
                const h8v af = *(const h8v*)&WP[(ks * 4 + kc) * 512 + lane * 8];
                acc = __builtin_amdgcn_mfma_f32_16x16x32_f16(af, bx[kc], acc, 0, 0, 0);
            }
            h4v pv;
            #pragma unroll
            for (int r = 0; r < 4; r++) pv[r] = (f16)acc[r];
            *(h4v*)&rep[w][l15 * 72 + ks * 16 + quad * 4] = pv;
        }
        #pragma unroll
        for (int j = 0; j < 2; j++){
            const h8v vv = *(const h8v*)&rep[w][(rrow + 8 * j) * 72 + rcol];
            *(h8v*)&OUT[((size_t)(b * NN + n0 + w * 16 + rrow + 8 * j)) * CB + rcol] = vv;
        }
    }

    h8v bw[4];
    #pragma unroll
    for (int kc = 0; kc < 4; kc++)
        bw[kc] = *(const h8v*)&wgp[(w * 4 + kc) * 512 + lane * 8];
    for (int ns = 0; ns < 4; ns++){
        f4v acc = {0.f, 0.f, 0.f, 0.f};
        #pragma unroll
        for (int kc = 0; kc < 4; kc++){
            const h8v af = *(const h8v*)&xT[ns * 16 + l15][kc * 32 + quad * 8];
            acc = __builtin_amdgcn_mfma_f32_16x16x32_f16(af, bw[kc], acc, 0, 0, 0);
        }
        h4v pv;
        #pragma unroll
        for (int r = 0; r < 4; r++) pv[r] = (f16)acc[r];
        *(h4v*)&rep[w][l15 * 72 + ns * 16 + quad * 4] = pv;
    }
    #pragma unroll
    for (int j = 0; j < 2; j++){
        const h8v vv = *(const h8v*)&rep[w][(rrow + 8 * j) * 72 + rcol];
        *(h8v*)&gbuf[((size_t)(b * CB + w * 16 + rrow + 8 * j)) * NN + n0 + rcol] = vv;
    }
}

// ---------------------------------------------------------------------------
// Kernel 2: fused attention + out-proj + residual. 32 queries/wave (2 sets),
// 128 queries/block, grid 256 (1 block/CU). Shared phi/g LDS reads amortize
// over 2x MFMAs: DS instr/CU -38%, staged L2 traffic halved, 2x per-wave ILP.
// Epilogue fO in f16 so 128 query-columns fit the staging overlay in 1 pass.
// ---------------------------------------------------------------------------
union StageOrOut {
    struct { f16 ph[2][64 * 72]; f16 g[2][64 * 72]; } s;   // 36864 B (K-loop)
    f16 fO[128][136];                                       // 34816 B (epilogue)
};

__global__ __launch_bounds__(256) void attn_kernel(
    const f16* __restrict__ thetaT, const f16* __restrict__ phiT,
    const f16* __restrict__ gbuf, const f16* __restrict__ wlp,
    const float* __restrict__ x, float* __restrict__ out)
{
    __shared__ __align__(16) StageOrOut sh;
    __shared__ __align__(16) f16 plds[4][32 * 72];  // P tile then y tile (32 q/wave)

    const int b  = blockIdx.x & 7;                  // XCD-swizzled
    const int q0 = (blockIdx.x >> 3) << 7;          // 32 blocks/batch, 128 q each
    const int t  = threadIdx.x;
    const int w = t >> 6, lane = t & 63, quad = lane >> 4, l15 = lane & 15;
    const int n0 = q0 + w * 32;

    // theta B-frags for the wave's two query sets
    h8v a0[2], a1[2];
    #pragma unroll
    for (int set = 0; set < 2; set++){
        const size_t tr = ((size_t)(b * NN + n0 + set * 16 + l15)) * CB;
        a0[set] = *(const h8v*)&thetaT[tr + quad * 8];
        a1[set] = *(const h8v*)&thetaT[tr + 32 + quad * 8];
    }

    // staging mapping (unchanged)
    const int r0 = t >> 3, r1 = r0 + 32, c = (t & 7) * 8;
    const f16* pphi0 = phiT + ((size_t)(b * NN + r0)) * CB + c;
    const f16* pphi1 = phiT + ((size_t)(b * NN + r1)) * CB + c;
    const f16* pg0   = gbuf + ((size_t)(b * CB + r0)) * NN + c;
    const f16* pg1   = gbuf + ((size_t)(b * CB + r1)) * NN + c;
    const int lA = r0 * 72 + c, lB = r1 * 72 + c;

    h8v nA = *(const h8v*)pphi0;
    h8v nB = *(const h8v*)pphi1;
    h8v nC = *(const h8v*)pg0;
    h8v nD = *(const h8v*)pg1;
    *(h8v*)&sh.s.ph[0][lA] = nA;  *(h8v*)&sh.s.ph[0][lB] = nB;
    *(h8v*)&sh.s.g [0][lA] = nC;  *(h8v*)&sh.s.g [0][lB] = nD;

    float mrun[2] = {-1e30f, -1e30f}, lrun[2] = {0.f, 0.f};
    f4v o[2][4];
    const f4v zf = {0.f, 0.f, 0.f, 0.f};
    #pragma unroll
    for (int set = 0; set < 2; set++)
        #pragma unroll
        for (int tt = 0; tt < 4; tt++) o[set][tt] = zf;

    f16* const pw = &plds[w][0];

    for (int kb = 0; kb < 64; kb++){
        const int pb = kb & 1;
        __syncthreads();
        if (kb < 63){
            pphi0 += (size_t)64 * CB;  pphi1 += (size_t)64 * CB;
            pg0 += 64;                 pg1 += 64;
            nA = *(const h8v*)pphi0;   nB = *(const h8v*)pphi1;
            nC = *(const h8v*)pg0;     nD = *(const h8v*)pg1;
        }

        // ---- S^T = phi(A) * theta(B) for both query sets (shared phi reads) ----
        f4v s[2][4];
        #pragma unroll
        for (int tt = 0; tt < 4; tt++){
            const f16* pr = &sh.s.ph[pb][(tt * 16 + l15) * 72];
            const h8v pb0 = *(const h8v*)(pr + quad * 8);
            const h8v pb1 = *(const h8v*)(pr + 32 + quad * 8);
            #pragma unroll
            for (int set = 0; set < 2; set++){
                f4v sv = zf;
                sv = __builtin_amdgcn_mfma_f32_16x16x32_f16(pb0, a0[set], sv, 0, 0, 0);
                sv = __builtin_amdgcn_mfma_f32_16x16x32_f16(pb1, a1[set], sv, 0, 0, 0);
                s[set][tt] = sv;
            }
        }
        // ---- online softmax per set (log2 domain; lane owns one query/set) ----
        #pragma unroll
        for (int set = 0; set < 2; set++){
            float smax = fmaxf(fmaxf(s[set][0][0], s[set][0][1]), fmaxf(s[set][0][2], s[set][0][3]));
            #pragma unroll
            for (int tt = 1; tt < 4; tt++)
                smax = fmaxf(smax, fmaxf(fmaxf(s[set][tt][0], s[set][tt][1]),
                                         fmaxf(s[set][tt][2], s[set][tt][3])));
            smax = fmaxf(smax, __shfl_xor(smax, 16));
            smax = fmaxf(smax, __shfl_xor(smax, 32));
            const float mn = fmaxf(mrun[set], smax);
            const float alpha = __builtin_amdgcn_exp2f(mrun[set] - mn);
            mrun[set] = mn;
            float lsum = 0.f;
            #pragma unroll
            for (int tt = 0; tt < 4; tt++){
                h4v pv;
                #pragma unroll
                for (int r = 0; r < 4; r++){
                    float p = __builtin_amdgcn_exp2f(s[set][tt][r] - mn);
                    lsum += p;
                    pv[r] = (f16)p;
                }
                *(h4v*)&pw[(set * 16 + l15) * 72 + tt * 16 + quad * 4] = pv;
            }
            lrun[set] = lrun[set] * alpha + lsum;
            #pragma unroll
            for (int tt = 0; tt < 4; tt++)
                #pragma unroll
                for (int r = 0; r < 4; r++)
                    o[set][tt][r] *= alpha;
        }

        // ---- reload P as B-frags per set ----
        h8v pa0[2], pa1[2];
        #pragma unroll
        for (int set = 0; set < 2; set++){
            pa0[set] = *(const h8v*)&pw[(set * 16 + l15) * 72 + quad * 8];
            pa1[set] = *(const h8v*)&pw[(set * 16 + l15) * 72 + 32 + quad * 8];
        }

        // ---- O^T += g(A) * P^T(B), shared g reads ----
        #pragma unroll
        for (int tt = 0; tt < 4; tt++){
            const f16* gr = &sh.s.g[pb][(tt * 16 + l15) * 72];
            const h8v gb0 = *(const h8v*)(gr + quad * 8);
            const h8v gb1 = *(const h8v*)(gr + 32 + quad * 8);
            #pragma unroll
            for (int set = 0; set < 2; set++){
                o[set][tt] = __builtin_amdgcn_mfma_f32_16x16x32_f16(gb0, pa0[set], o[set][tt], 0, 0, 0);
                o[set][tt] = __builtin_amdgcn_mfma_f32_16x16x32_f16(gb1, pa1[set], o[set][tt], 0, 0, 0);
            }
        }

        if (kb < 63){
            const int nb = pb ^ 1;
            *(h8v*)&sh.s.ph[nb][lA] = nA;  *(h8v*)&sh.s.ph[nb][lB] = nB;
            *(h8v*)&sh.s.g [nb][lA] = nC;  *(h8v*)&sh.s.g [nb][lB] = nD;
        }
    }

    // ---- normalize and write y tiles to wave-private LDS ----
    #pragma unroll
    for (int set = 0; set < 2; set++){
        lrun[set] += __shfl_xor(lrun[set], 16);
        lrun[set] += __shfl_xor(lrun[set], 32);
        const float inv = 1.0f / lrun[set];
        #pragma unroll
        for (int tt = 0; tt < 4; tt++){
            h4v yv;
            #pragma unroll
            for (int r = 0; r < 4; r++) yv[r] = (f16)(o[set][tt][r] * inv);
            *(h4v*)&pw[(set * 16 + l15) * 72 + tt * 16 + quad * 4] = yv;
        }
    }

    __syncthreads();   // staging region dead -> overlay fO

    // ---- out-GEMM: D[c][q] = wl(A) * y(B), both sets; fO in f16 ----
    #pragma unroll
    for (int set = 0; set < 2; set++){
        const h8v yB0 = *(const h8v*)&pw[(set * 16 + l15) * 72 + quad * 8];
        const h8v yB1 = *(const h8v*)&pw[(set * 16 + l15) * 72 + 32 + quad * 8];
        #pragma unroll
        for (int cs = 0; cs < 8; cs++){
            const h8v wa0 = *(const h8v*)&wlp[(cs * 2 + 0) * 512 + lane * 8];
            const h8v wa1 = *(const h8v*)&wlp[(cs * 2 + 1) * 512 + lane * 8];
            f4v acc = zf;
            acc = __builtin_amdgcn_mfma_f32_16x16x32_f16(wa0, yB0, acc, 0, 0, 0);
            acc = __builtin_amdgcn_mfma_f32_16x16x32_f16(wa1, yB1, acc, 0, 0, 0);
            #pragma unroll
            for (int r = 0; r < 4; r++)
                sh.fO[cs * 16 + quad * 4 + r][w * 32 + set * 16 + l15] = (f16)acc[r];
        }
    }
    __syncthreads();

    // ---- residual RMW: fully coalesced (16 lanes x 8 f32 = 512B per row) ----
    #pragma unroll
    for (int i = 0; i < 8; i++){
        const int row = i * 16 + (t >> 4);
        const int jq  = (t & 15) * 8;
        const h8v v8 = *(const h8v*)&sh.fO[row][jq];
        const size_t idx = ((size_t)(b * CC + row)) * NN + q0 + jq;
        const f4v x0 = *(const f4v*)&x[idx];
        const f4v x1 = *(const f4v*)&x[idx + 4];
        f4v o0, o1;
        #pragma unroll
        for (int r = 0; r < 4; r++){ o0[r] = (float)v8[r] + x0[r]; o1[r] = (float)v8[r + 4] + x1[r]; }
        *(f4v*)&out[idx]     = o0;
        *(f4v*)&out[idx + 4] = o1;
    }
}

extern "C" void kernel_launch(void* const* d_in, const int* in_sizes, int n_in,
                              void* d_out, int out_size, void* d_ws, size_t ws_size,
                              hipStream_t stream)
{
    const float* x   = (const float*)d_in[0];
    const float* wth = (const float*)d_in[1];
    const float* wph = (const float*)d_in[2];
    const float* wg  = (const float*)d_in[3];
    const float* wl  = (const float*)d_in[4];
    float* out = (float*)d_out;

    f16* thetaT = (f16*)d_ws;
    f16* phiT   = thetaT + (size_t)NB * NN * CB;
    f16* gbuf   = phiT   + (size_t)NB * NN * CB;
    f16* wthp   = gbuf   + (size_t)NB * NN * CB;
    f16* wphp   = wthp + 8192;
    f16* wgp    = wphp + 8192;
    f16* wlp    = wgp  + 8192;

    pack_w<<<8, 256, 0, stream>>>(wth, wph, wg, wl, wthp, wphp, wgp, wlp);
    proj_kernel<<<NB * 64, 256, 0, stream>>>(x, wthp, wphp, wgp, thetaT, phiT, gbuf);
    attn_kernel<<<NB * 32, 256, 0, stream>>>(thetaT, phiT, gbuf, wlp, x, out);
}

// Round 17
// 159.861 us; speedup vs baseline: 1.1088x; 1.1088x over previous
//
#include <hip/hip_runtime.h>
#include <stdint.h>

typedef _Float16 h8v __attribute__((ext_vector_type(8)));
typedef _Float16 h4v __attribute__((ext_vector_type(4)));
typedef float f4v __attribute__((ext_vector_type(4)));
typedef _Float16 f16;

#define NB 8
#define CC 128
#define CB 64
#define NN 4096
#define L2E 1.4426950408889634f

// ---------------------------------------------------------------------------
// Kernel 0: pack weights into f16 MFMA-fragment order (once per launch).
// Wp[((ks*4+kc)*64 + lane)*8 + j] <- W[(ks*16+(lane&15))*CC + kc*32+((lane>>4)&3)*8 + j]
// wth pre-scaled by log2(e) for attn's exp2 softmax.
// ---------------------------------------------------------------------------
__global__ __launch_bounds__(256) void pack_w(
    const float* __restrict__ wth, const float* __restrict__ wph,
    const float* __restrict__ wg,  const float* __restrict__ wl,
    f16* __restrict__ wthp, f16* __restrict__ wphp,
    f16* __restrict__ wgp,  f16* __restrict__ wlp)
{
    const int t = blockIdx.x * 256 + threadIdx.x;      // 2048 threads
    for (int i = t; i < 8192; i += 2048){
        const int j = i & 7, lane = (i >> 3) & 63, kc = (i >> 9) & 3, ks = i >> 11;
        const int row = ks * 16 + (lane & 15);
        const int col = kc * 32 + ((lane >> 4) & 3) * 8 + j;
        wthp[i] = (f16)(wth[row * CC + col] * L2E);
        wphp[i] = (f16)(wph[row * CC + col]);
        wgp [i] = (f16)(wg [row * CC + col]);
    }
    for (int i = t; i < 8192; i += 2048){
        const int j = i & 7, lane = (i >> 3) & 63, kc = (i >> 9) & 1, cs = i >> 10;
        const int row = cs * 16 + (lane & 15);
        const int col = kc * 32 + ((lane >> 4) & 3) * 8 + j;
        wlp[i] = (f16)(wl[row * CB + col]);
    }
}

// ---------------------------------------------------------------------------
// Kernel 1: projections. Weight fragments from packed f16 buffers (coalesced,
// L1-resident). Epilogue repack via wave-private LDS -> full-line h8v stores.
// ---------------------------------------------------------------------------
__global__ __launch_bounds__(256) void proj_kernel(
    const float* __restrict__ x, const f16* __restrict__ wthp,
    const f16* __restrict__ wphp, const f16* __restrict__ wgp,
    f16* __restrict__ thetaT, f16* __restrict__ phiT, f16* __restrict__ gbuf)
{
    __shared__ __align__(16) f16 xT[64][136];
    __shared__ __align__(16) f16 rep[4][16 * 72];
    const int b  = blockIdx.x & 7;
    const int n0 = (blockIdx.x >> 3) << 6;
    const int t  = threadIdx.x;

    #pragma unroll
    for (int i = 0; i < 8; i++){
        int v  = t + 256 * i;
        int c  = v >> 4;
        int j0 = (v & 15) << 2;
        const f4v xv = *(const f4v*)&x[((size_t)(b * CC + c)) * NN + n0 + j0];
        #pragma unroll
        for (int jj = 0; jj < 4; jj++) xT[j0 + jj][c] = (f16)xv[jj];
    }
    __syncthreads();

    const int w = t >> 6, lane = t & 63, quad = lane >> 4, l15 = lane & 15;
    const int rrow = lane >> 3, rcol = (lane & 7) * 8;

    h8v bx[4];
    #pragma unroll
    for (int kc = 0; kc < 4; kc++)
        bx[kc] = *(const h8v*)&xT[w * 16 + l15][kc * 32 + quad * 8];

    #pragma unroll
    for (int m3 = 0; m3 < 2; m3++){
        const f16* WP = (m3 == 0) ? wthp : wphp;
        f16* OUT      = (m3 == 0) ? thetaT : phiT;
        for (int ks = 0; ks < 4; ks++){
            f4v acc = {0.f, 0.f, 0.f, 0.f};
            #pragma unroll
            for (int kc = 0; kc < 4; kc++){
                const h8v af = *(const h8v*)&WP[(ks * 4 + kc) * 512 + lane * 8];
                acc = __builtin_amdgcn_mfma_f32_16x16x32_f16(af, bx[kc], acc, 0, 0, 0);
            }
            h4v pv;
            #pragma unroll
            for (int r = 0; r < 4; r++) pv[r] = (f16)acc[r];
            *(h4v*)&rep[w][l15 * 72 + ks * 16 + quad * 4] = pv;
        }
        #pragma unroll
        for (int j = 0; j < 2; j++){
            const h8v vv = *(const h8v*)&rep[w][(rrow + 8 * j) * 72 + rcol];
            *(h8v*)&OUT[((size_t)(b * NN + n0 + w * 16 + rrow + 8 * j)) * CB + rcol] = vv;
        }
    }

    h8v bw[4];
    #pragma unroll
    for (int kc = 0; kc < 4; kc++)
        bw[kc] = *(const h8v*)&wgp[(w * 4 + kc) * 512 + lane * 8];
    for (int ns = 0; ns < 4; ns++){
        f4v acc = {0.f, 0.f, 0.f, 0.f};
        #pragma unroll
        for (int kc = 0; kc < 4; kc++){
            const h8v af = *(const h8v*)&xT[ns * 16 + l15][kc * 32 + quad * 8];
            acc = __builtin_amdgcn_mfma_f32_16x16x32_f16(af, bw[kc], acc, 0, 0, 0);
        }
        h4v pv;
        #pragma unroll
        for (int r = 0; r < 4; r++) pv[r] = (f16)acc[r];
        *(h4v*)&rep[w][l15 * 72 + ns * 16 + quad * 4] = pv;
    }
    #pragma unroll
    for (int j = 0; j < 2; j++){
        const h8v vv = *(const h8v*)&rep[w][(rrow + 8 * j) * 72 + rcol];
        *(h8v*)&gbuf[((size_t)(b * CB + w * 16 + rrow + 8 * j)) * NN + n0 + rcol] = vv;
    }
}

// ---------------------------------------------------------------------------
// Kernel 2: fused attention + out-proj + residual (R13-exact, proven stable).
// 16 q/wave, 64 q/block, grid 512 = 2 blocks/CU. Transposed-S, P via
// wave-private LDS round-trip, K32 PV, overlay epilogue.
// ---------------------------------------------------------------------------
union StageOrOut {
    struct { f16 ph[2][64 * 72]; f16 g[2][64 * 72]; } s;   // 36864 B (K-loop)
    f16 fO[128][136];                                       // 34816 B (epilogue)
};

__global__ __launch_bounds__(256) void attn_kernel(
    const f16* __restrict__ thetaT, const f16* __restrict__ phiT,
    const f16* __restrict__ gbuf, const f16* __restrict__ wlp,
    const float* __restrict__ x, float* __restrict__ out)
{
    __shared__ __align__(16) StageOrOut sh;
    __shared__ __align__(16) f16 plds[4][16 * 72];  // P tile, then y tile

    const int b  = blockIdx.x & 7;                  // XCD-swizzled
    const int q0 = (blockIdx.x >> 3) << 6;
    const int t  = threadIdx.x;
    const int w = t >> 6, lane = t & 63, quad = lane >> 4, l15 = lane & 15;
    const int n0 = q0 + w * 16;

    const size_t trow = ((size_t)(b * NN + n0 + l15)) * CB;
    const h8v a0 = *(const h8v*)&thetaT[trow + quad * 8];
    const h8v a1 = *(const h8v*)&thetaT[trow + 32 + quad * 8];

    const int r0 = t >> 3, r1 = r0 + 32, c = (t & 7) * 8;
    const f16* pphi0 = phiT + ((size_t)(b * NN + r0)) * CB + c;
    const f16* pphi1 = phiT + ((size_t)(b * NN + r1)) * CB + c;
    const f16* pg0   = gbuf + ((size_t)(b * CB + r0)) * NN + c;
    const f16* pg1   = gbuf + ((size_t)(b * CB + r1)) * NN + c;
    const int lA = r0 * 72 + c, lB = r1 * 72 + c;

    h8v nA = *(const h8v*)pphi0;
    h8v nB = *(const h8v*)pphi1;
    h8v nC = *(const h8v*)pg0;
    h8v nD = *(const h8v*)pg1;
    *(h8v*)&sh.s.ph[0][lA] = nA;  *(h8v*)&sh.s.ph[0][lB] = nB;
    *(h8v*)&sh.s.g [0][lA] = nC;  *(h8v*)&sh.s.g [0][lB] = nD;

    float mrun = -1e30f, lrun = 0.f;
    f4v o[4];
    const f4v zf = {0.f, 0.f, 0.f, 0.f};
    #pragma unroll
    for (int tt = 0; tt < 4; tt++) o[tt] = zf;

    f16* const pw = &plds[w][0];

    for (int kb = 0; kb < 64; kb++){
        const int pb = kb & 1;
        __syncthreads();
        if (kb < 63){
            pphi0 += (size_t)64 * CB;  pphi1 += (size_t)64 * CB;
            pg0 += 64;                 pg1 += 64;
            nA = *(const h8v*)pphi0;   nB = *(const h8v*)pphi1;
            nC = *(const h8v*)pg0;     nD = *(const h8v*)pg1;
        }

        // ---- S^T = phi(A) * theta(B): rows=keys, cols=queries ----
        f4v s[4];
        #pragma unroll
        for (int tt = 0; tt < 4; tt++){
            const f16* pr = &sh.s.ph[pb][(tt * 16 + l15) * 72];
            const h8v pb0 = *(const h8v*)(pr + quad * 8);
            const h8v pb1 = *(const h8v*)(pr + 32 + quad * 8);
            f4v sv = zf;
            sv = __builtin_amdgcn_mfma_f32_16x16x32_f16(pb0, a0, sv, 0, 0, 0);
            sv = __builtin_amdgcn_mfma_f32_16x16x32_f16(pb1, a1, sv, 0, 0, 0);
            s[tt] = sv;
        }
        // ---- online softmax (log2 domain; lane owns query l15) ----
        float smax = fmaxf(fmaxf(s[0][0], s[0][1]), fmaxf(s[0][2], s[0][3]));
        #pragma unroll
        for (int tt = 1; tt < 4; tt++)
            smax = fmaxf(smax, fmaxf(fmaxf(s[tt][0], s[tt][1]), fmaxf(s[tt][2], s[tt][3])));
        smax = fmaxf(smax, __shfl_xor(smax, 16));
        smax = fmaxf(smax, __shfl_xor(smax, 32));
        const float mn = fmaxf(mrun, smax);
        const float alpha = __builtin_amdgcn_exp2f(mrun - mn);
        mrun = mn;
        float lsum = 0.f;
        #pragma unroll
        for (int tt = 0; tt < 4; tt++){
            h4v pv;
            #pragma unroll
            for (int r = 0; r < 4; r++){
                float p = __builtin_amdgcn_exp2f(s[tt][r] - mn);
                lsum += p;
                pv[r] = (f16)p;
            }
            *(h4v*)&pw[l15 * 72 + tt * 16 + quad * 4] = pv;
        }
        lrun = lrun * alpha + lsum;
        #pragma unroll
        for (int tt = 0; tt < 4; tt++)
            #pragma unroll
            for (int r = 0; r < 4; r++)
                o[tt][r] *= alpha;

        const h8v pa0 = *(const h8v*)&pw[l15 * 72 + quad * 8];
        const h8v pa1 = *(const h8v*)&pw[l15 * 72 + 32 + quad * 8];

        // ---- O^T += g(A) * P^T(B) ----
        #pragma unroll
        for (int tt = 0; tt < 4; tt++){
            const f16* gr = &sh.s.g[pb][(tt * 16 + l15) * 72];
            const h8v gb0 = *(const h8v*)(gr + quad * 8);
            const h8v gb1 = *(const h8v*)(gr + 32 + quad * 8);
            o[tt] = __builtin_amdgcn_mfma_f32_16x16x32_f16(gb0, pa0, o[tt], 0, 0, 0);
            o[tt] = __builtin_amdgcn_mfma_f32_16x16x32_f16(gb1, pa1, o[tt], 0, 0, 0);
        }

        if (kb < 63){
            const int nb = pb ^ 1;
            *(h8v*)&sh.s.ph[nb][lA] = nA;  *(h8v*)&sh.s.ph[nb][lB] = nB;
            *(h8v*)&sh.s.g [nb][lA] = nC;  *(h8v*)&sh.s.g [nb][lB] = nD;
        }
    }

    lrun += __shfl_xor(lrun, 16);
    lrun += __shfl_xor(lrun, 32);
    const float inv = 1.0f / lrun;

    #pragma unroll
    for (int tt = 0; tt < 4; tt++){
        h4v yv;
        #pragma unroll
        for (int r = 0; r < 4; r++) yv[r] = (f16)(o[tt][r] * inv);
        *(h4v*)&pw[l15 * 72 + tt * 16 + quad * 4] = yv;
    }

    __syncthreads();   // staging region dead -> overlay fO

    // ---- out-GEMM: D[c][q] = wl(A) * y(B); packed wl fragments ----
    const h8v yB0 = *(const h8v*)&pw[l15 * 72 + quad * 8];
    const h8v yB1 = *(const h8v*)&pw[l15 * 72 + 32 + quad * 8];
    #pragma unroll
    for (int cs = 0; cs < 8; cs++){
        const h8v wa0 = *(const h8v*)&wlp[(cs * 2 + 0) * 512 + lane * 8];
        const h8v wa1 = *(const h8v*)&wlp[(cs * 2 + 1) * 512 + lane * 8];
        f4v acc = zf;
        acc = __builtin_amdgcn_mfma_f32_16x16x32_f16(wa0, yB0, acc, 0, 0, 0);
        acc = __builtin_amdgcn_mfma_f32_16x16x32_f16(wa1, yB1, acc, 0, 0, 0);
        #pragma unroll
        for (int r = 0; r < 4; r++)
            sh.fO[cs * 16 + quad * 4 + r][w * 16 + l15] = (f16)acc[r];
    }
    __syncthreads();

    // ---- residual RMW: fully coalesced float4 ----
    #pragma unroll
    for (int i = 0; i < 8; i++){
        const int row = i * 16 + (t >> 4);
        const int nf  = (t & 15) * 4;
        const h4v v = *(const h4v*)&sh.fO[row][nf];
        const size_t idx = ((size_t)(b * CC + row)) * NN + q0 + nf;
        const f4v xv = *(const f4v*)&x[idx];
        f4v ov;
        #pragma unroll
        for (int r = 0; r < 4; r++) ov[r] = (float)v[r] + xv[r];
        *(f4v*)&out[idx] = ov;
    }
}

extern "C" void kernel_launch(void* const* d_in, const int* in_sizes, int n_in,
                              void* d_out, int out_size, void* d_ws, size_t ws_size,
                              hipStream_t stream)
{
    const float* x   = (const float*)d_in[0];
    const float* wth = (const float*)d_in[1];
    const float* wph = (const float*)d_in[2];
    const float* wg  = (const float*)d_in[3];
    const float* wl  = (const float*)d_in[4];
    float* out = (float*)d_out;

    f16* thetaT = (f16*)d_ws;
    f16* phiT   = thetaT + (size_t)NB * NN * CB;
    f16* gbuf   = phiT   + (size_t)NB * NN * CB;
    f16* wthp   = gbuf   + (size_t)NB * NN * CB;
    f16* wphp   = wthp + 8192;
    f16* wgp    = wphp + 8192;
    f16* wlp    = wgp  + 8192;

    pack_w<<<8, 256, 0, stream>>>(wth, wph, wg, wl, wthp, wphp, wgp, wlp);
    proj_kernel<<<NB * 64, 256, 0, stream>>>(x, wthp, wphp, wgp, thetaT, phiT, gbuf);
    attn_kernel<<<NB * 64, 256, 0, stream>>>(thetaT, phiT, gbuf, wlp, x, out);
}